// Round 1
// baseline (108.112 us; speedup 1.0000x reference)
//
#include <hip/hip_runtime.h>
#include <hip/hip_bf16.h>
#include <math.h>

#define NB 512
#define NT 256
#define NC 384
#define NH 64

typedef __bf16 bf16x8 __attribute__((ext_vector_type(8)));
typedef unsigned short u16x8 __attribute__((ext_vector_type(8)));
typedef float f32x4 __attribute__((ext_vector_type(4)));

// LDS layout (ushort units)
#define OFF_Q   0
#define LDQ     72
#define OFF_K   18432
#define LDK     72
#define OFF_VT  36864
#define LDVT    264
#define OFF_WT  53760
#define LDWT    392
#define OFF_PW  53760      // overlays Wt after projections are done
#define LDPW    40
#define SMEM_U16 78848     // 157,696 bytes total

__device__ __forceinline__ unsigned short f2bf(float f) {
    union { float f; unsigned u; } v; v.f = f;
    unsigned r = v.u + 0x7FFFu + ((v.u >> 16) & 1u);   // round-to-nearest-even
    return (unsigned short)(r >> 16);
}

__device__ __forceinline__ f32x4 mfma16(bf16x8 a, bf16x8 b, f32x4 c) {
    return __builtin_amdgcn_mfma_f32_16x16x32_bf16(a, b, c, 0, 0, 0);
}

__global__ __launch_bounds__(512, 2) void head_fused(
    const float* __restrict__ x, const float* __restrict__ Wq,
    const float* __restrict__ Wk, const float* __restrict__ Wv,
    float* __restrict__ out)
{
    __shared__ __align__(16) unsigned short SM[SMEM_U16];

    const int b    = blockIdx.x;
    const int tid  = threadIdx.x;
    const int w    = tid >> 6;       // wave 0..7
    const int lane = tid & 63;
    const int g    = lane >> 4;      // 16-lane group 0..3
    const int col  = lane & 15;
    const int mt0  = w;              // balanced causal pairing: tiles {w, 15-w}
    const int mt1  = 15 - w;

    const f32x4 fzero = {0.f, 0.f, 0.f, 0.f};
    const float* xb = x + (size_t)b * NT * NC;

    // ---------------- cache x A-fragments (bf16) in registers ----------------
    bf16x8 xfrag[2][12];
    #pragma unroll
    for (int mt = 0; mt < 2; ++mt) {
        const int MTm = mt ? mt1 : mt0;
        const float* xrow = xb + (MTm * 16 + col) * NC;
        #pragma unroll
        for (int kk = 0; kk < 12; ++kk) {
            const float4 lo = *reinterpret_cast<const float4*>(xrow + kk * 32 + g * 8);
            const float4 hi = *reinterpret_cast<const float4*>(xrow + kk * 32 + g * 8 + 4);
            u16x8 u;
            u[0] = f2bf(lo.x); u[1] = f2bf(lo.y); u[2] = f2bf(lo.z); u[3] = f2bf(lo.w);
            u[4] = f2bf(hi.x); u[5] = f2bf(hi.y); u[6] = f2bf(hi.z); u[7] = f2bf(hi.w);
            xfrag[mt][kk] = __builtin_bit_cast(bf16x8, u);
        }
    }

    // ---------------- projections: Q, K, V (one W staged at a time) ----------
    const float* Ws[3] = { Wq, Wk, Wv };
    #pragma unroll
    for (int pass = 0; pass < 3; ++pass) {
        const float* W = Ws[pass];
        // stage W^T into LDS (bf16), coalesced reads
        for (int idx = tid; idx < NC * NH; idx += 512) {
            const int c = idx >> 6;
            const int h = idx & 63;
            SM[OFF_WT + h * LDWT + c] = f2bf(W[idx]);
        }
        __syncthreads();

        #pragma unroll
        for (int mt = 0; mt < 2; ++mt) {
            const int MTm = mt ? mt1 : mt0;
            f32x4 acc[4];
            acc[0] = fzero; acc[1] = fzero; acc[2] = fzero; acc[3] = fzero;
            #pragma unroll
            for (int kk = 0; kk < 12; ++kk) {
                const bf16x8 a = xfrag[mt][kk];
                #pragma unroll
                for (int n = 0; n < 4; ++n) {
                    const bf16x8 bb = *reinterpret_cast<const bf16x8*>(
                        &SM[OFF_WT + (n * 16 + col) * LDWT + kk * 32 + g * 8]);
                    acc[n] = mfma16(a, bb, acc[n]);
                }
            }
            const int tb = MTm * 16 + g * 4;
            if (pass < 2) {
                const int base = (pass == 0) ? OFF_Q : OFF_K;
                #pragma unroll
                for (int n = 0; n < 4; ++n)
                    #pragma unroll
                    for (int r = 0; r < 4; ++r)
                        SM[base + (tb + r) * LDQ + n * 16 + col] = f2bf(acc[n][r]);
            } else {
                // V stored transposed: Vt[h][t]
                #pragma unroll
                for (int n = 0; n < 4; ++n)
                    #pragma unroll
                    for (int r = 0; r < 4; ++r)
                        SM[OFF_VT + (n * 16 + col) * LDVT + tb + r] = f2bf(acc[n][r]);
            }
        }
        __syncthreads();
    }

    // ---------------- scores: S = Q K^T (causal tiles only) ------------------
    f32x4 sc[2][16];
    #pragma unroll
    for (int mt = 0; mt < 2; ++mt) {
        const int MTm = mt ? mt1 : mt0;
        bf16x8 qa[2];
        #pragma unroll
        for (int kk = 0; kk < 2; ++kk)
            qa[kk] = *reinterpret_cast<const bf16x8*>(
                &SM[OFF_Q + (MTm * 16 + col) * LDQ + kk * 32 + g * 8]);
        #pragma unroll
        for (int nt = 0; nt < 16; ++nt) {
            if (nt <= MTm) {
                f32x4 a = fzero;
                #pragma unroll
                for (int kk = 0; kk < 2; ++kk) {
                    const bf16x8 kb = *reinterpret_cast<const bf16x8*>(
                        &SM[OFF_K + (nt * 16 + col) * LDK + kk * 32 + g * 8]);
                    a = mfma16(qa[kk], kb, a);
                }
                sc[mt][nt] = a;
            }
        }
    }

    // ---------------- softmax (scale, mask, exp; unnormalized P) -------------
    float inv_sum[2][4];
    #pragma unroll
    for (int mt = 0; mt < 2; ++mt) {
        const int MTm = mt ? mt1 : mt0;
        #pragma unroll
        for (int r = 0; r < 4; ++r) {
            float m = -INFINITY;
            #pragma unroll
            for (int nt = 0; nt < 16; ++nt) {
                if (nt <= MTm) {
                    float v = sc[mt][nt][r] * 0.125f;
                    if (nt == MTm && col > g * 4 + r) v = -INFINITY;  // causal mask in diagonal tile
                    sc[mt][nt][r] = v;
                    m = fmaxf(m, v);
                }
            }
            m = fmaxf(m, __shfl_xor(m, 1));
            m = fmaxf(m, __shfl_xor(m, 2));
            m = fmaxf(m, __shfl_xor(m, 4));
            m = fmaxf(m, __shfl_xor(m, 8));
            float s = 0.f;
            #pragma unroll
            for (int nt = 0; nt < 16; ++nt) {
                if (nt <= MTm) {
                    const float p = __expf(sc[mt][nt][r] - m);
                    sc[mt][nt][r] = p;
                    s += p;
                }
            }
            s += __shfl_xor(s, 1);
            s += __shfl_xor(s, 2);
            s += __shfl_xor(s, 4);
            s += __shfl_xor(s, 8);
            inv_sum[mt][r] = 1.0f / s;
        }
    }

    // ---------------- PV: O = P V, staged per-wave through LDS ---------------
    f32x4 oacc[2][4];
    #pragma unroll
    for (int mt = 0; mt < 2; ++mt)
        #pragma unroll
        for (int n = 0; n < 4; ++n) oacc[mt][n] = fzero;

    #pragma unroll
    for (int scn = 0; scn < 8; ++scn) {   // s-chunks of 32
        #pragma unroll
        for (int mt = 0; mt < 2; ++mt) {
            const int MTm = mt ? mt1 : mt0;
            if (2 * scn <= MTm) {
                #pragma unroll
                for (int half = 0; half < 2; ++half) {
                    const int nt = 2 * scn + half;
                    #pragma unroll
                    for (int r = 0; r < 4; ++r) {
                        float p = 0.f;
                        if (nt <= MTm) p = sc[mt][nt][r];
                        SM[OFF_PW + ((w * 2 + mt) * 16 + g * 4 + r) * LDPW + half * 16 + col] = f2bf(p);
                    }
                }
            }
        }
        __syncthreads();
        #pragma unroll
        for (int mt = 0; mt < 2; ++mt) {
            const int MTm = mt ? mt1 : mt0;
            if (2 * scn <= MTm) {
                const bf16x8 pa = *reinterpret_cast<const bf16x8*>(
                    &SM[OFF_PW + ((w * 2 + mt) * 16 + col) * LDPW + g * 8]);
                #pragma unroll
                for (int n = 0; n < 4; ++n) {
                    const bf16x8 vb = *reinterpret_cast<const bf16x8*>(
                        &SM[OFF_VT + (n * 16 + col) * LDVT + scn * 32 + g * 8]);
                    oacc[mt][n] = mfma16(pa, vb, oacc[mt][n]);
                }
            }
        }
        __syncthreads();
    }

    // ---------------- normalize + write out ----------------------------------
    #pragma unroll
    for (int mt = 0; mt < 2; ++mt) {
        const int MTm = mt ? mt1 : mt0;
        #pragma unroll
        for (int n = 0; n < 4; ++n)
            #pragma unroll
            for (int r = 0; r < 4; ++r) {
                const int t = MTm * 16 + g * 4 + r;
                out[((size_t)b * NT + t) * NH + n * 16 + col] = oacc[mt][n][r] * inv_sum[mt][r];
            }
    }
}

extern "C" void kernel_launch(void* const* d_in, const int* in_sizes, int n_in,
                              void* d_out, int out_size, void* d_ws, size_t ws_size,
                              hipStream_t stream) {
    (void)in_sizes; (void)n_in; (void)out_size; (void)d_ws; (void)ws_size;
    const float* x  = (const float*)d_in[0];
    const float* wq = (const float*)d_in[1];
    const float* wk = (const float*)d_in[2];
    const float* wv = (const float*)d_in[3];
    float* o = (float*)d_out;
    head_fused<<<dim3(NB), dim3(512), 0, stream>>>(x, wq, wk, wv, o);
}